// Round 13
// baseline (197.067 us; speedup 1.0000x reference)
//
#include <hip/hip_runtime.h>
#include <math.h>

// Problem constants
#define Bsz 2
#define Tsz 2048
#define Csz 768
#define Hsz 12
#define C3  2304      // 3*C
#define WIN 256
#define LN_EPS 1e-5f

// Q pre-scale: D^-0.5 * log2(e), folded into the QKV GEMM epilogue so the
// attention kernel works in the exp2 domain with no per-element multiplies.
#define QSCALE 0.1803368801111137f

typedef short bf16x8 __attribute__((ext_vector_type(8)));  // 8 bf16 (4 VGPRs)
typedef float f32x4  __attribute__((ext_vector_type(4)));

// fp32 -> bf16 round-to-nearest-even
__device__ __forceinline__ unsigned short f2b(float f) {
    unsigned int u = __float_as_uint(f);
    u = (u + 0x7fffu + ((u >> 16) & 1u)) >> 16;
    return (unsigned short)u;
}

// raw v_exp_f32 (exp2). ocml exp2f without fast-math adds ~5 insts of
// denormal fixup; inputs here are |x| <~ 12, nothing denormal matters.
__device__ __forceinline__ float fast_exp2(float x) {
    float r;
    asm("v_exp_f32 %0, %1" : "=v"(r) : "v"(x));
    return r;
}

// ---------------------------------------------------------------------------
// Fused prep: convert_bf16 | transpose_conv(wq) | transpose_conv(wp) | sel.
// Block ranges: [0,3072) convert; [3072,4800) wq-transpose (72x24);
// [4800,5376) wp-transpose (24x24); [5376,9472) sel rows.
// ---------------------------------------------------------------------------
__global__ __launch_bounds__(256) void prep_fused(
    const float* __restrict__ x, unsigned short* __restrict__ xb,
    const float* __restrict__ c_attn_w, unsigned short* __restrict__ wq,
    const float* __restrict__ c_proj_w, unsigned short* __restrict__ wp,
    const float* __restrict__ mr, const float* __restrict__ ln_w,
    const float* __restrict__ ln_b, const float* __restrict__ scale_p,
    const float* __restrict__ sel_w, const float* __restrict__ sel_b,
    float* __restrict__ sel)
{
    __shared__ float tile[32][33];
    __shared__ float red1[256];
    __shared__ float red2[256];
    __shared__ float mu_sh, rstd_sh;

    const int blk = blockIdx.x;
    const int tid = threadIdx.x;

    if (blk < 3072) {
        int idx = blk * 256 + tid;
        float4 v = *(const float4*)(x + (size_t)idx * 4);
        unsigned int lo = (unsigned int)f2b(v.x) | ((unsigned int)f2b(v.y) << 16);
        unsigned int hi = (unsigned int)f2b(v.z) | ((unsigned int)f2b(v.w) << 16);
        uint2 o; o.x = lo; o.y = hi;
        *(uint2*)(xb + (size_t)idx * 4) = o;
        return;
    }
    if (blk < 5376) {
        const float* src; unsigned short* dst; int K, N, n0, k0;
        if (blk < 4800) {
            int i = blk - 3072;             // wq: grid (72, 24)
            src = c_attn_w; dst = wq; K = Csz; N = C3;
            n0 = (i % 72) * 32; k0 = (i / 72) * 32;
        } else {
            int i = blk - 4800;             // wp: grid (24, 24)
            src = c_proj_w; dst = wp; K = Csz; N = Csz;
            n0 = (i % 24) * 32; k0 = (i / 24) * 32;
        }
        const int tx = tid & 31, ty = tid >> 5;   // 32 x 8
        #pragma unroll
        for (int p = 0; p < 4; ++p)
            tile[ty + p * 8][tx] = src[(size_t)(k0 + ty + p * 8) * N + n0 + tx];
        __syncthreads();
        #pragma unroll
        for (int p = 0; p < 4; ++p)
            dst[(size_t)(n0 + ty + p * 8) * K + k0 + tx] = f2b(tile[tx][ty + p * 8]);
        return;
    }

    const int r = blk - 5376;
    const float* row = mr + (size_t)r * Csz;

    float s = 0.f, s2 = 0.f;
    for (int c = tid; c < Csz; c += 256) {
        float xv = row[c];
        s += xv; s2 += xv * xv;
    }
    red1[tid] = s; red2[tid] = s2;
    __syncthreads();
    for (int st = 128; st > 0; st >>= 1) {
        if (tid < st) { red1[tid] += red1[tid + st]; red2[tid] += red2[tid + st]; }
        __syncthreads();
    }
    if (tid == 0) {
        float mu = red1[0] * (1.f / Csz);
        float var = red2[0] * (1.f / Csz) - mu * mu;
        mu_sh = mu;
        rstd_sh = rsqrtf(var + LN_EPS);
    }
    __syncthreads();
    const float mu = mu_sh, rstd = rstd_sh;

    float dot = 0.f;
    for (int c = tid; c < Csz; c += 256) {
        float xn = (row[c] - mu) * rstd * ln_w[c] + ln_b[c];
        dot += xn * sel_w[c];
    }
    red1[tid] = dot;
    __syncthreads();
    for (int st = 128; st > 0; st >>= 1) {
        if (tid < st) red1[tid] += red1[tid + st];
        __syncthreads();
    }
    if (tid == 0) {
        float z = scale_p[0] * red1[0] + sel_b[0];
        sel[r] = 0.5f + 0.5f / (1.f + __expf(-z));
    }
}

// ---------------------------------------------------------------------------
// bf16 MFMA GEMM, B^T input. Two epilogue MODEs (R11, proven).
// MODE 0 (proj): C fp32 = acc + bias.
// MODE 1 (QKV): Q (bf16, *QSCALE) -> qb[M][768]; K/V directly in KP/VP
//   frag-linear order (inverse pack mappings). Main loop = R7 structure.
// ---------------------------------------------------------------------------
template<int MODE>
__global__ __launch_bounds__(256) void gemm_bt_mfma(
    const unsigned short* __restrict__ A, const unsigned short* __restrict__ BT,
    const float* __restrict__ bias, void* __restrict__ Cout,
    unsigned short* __restrict__ KP, unsigned short* __restrict__ VP,
    int M, int N, int K)
{
    __shared__ unsigned short As[128 * 32];
    __shared__ unsigned short Bs[128 * 32];

    const int tid = threadIdx.x;
    const int lane = tid & 63, widx = tid >> 6;
    const int lm = lane & 15, quad = lane >> 4;
    const int wm = widx >> 1, wn = widx & 1;
    const int m0 = blockIdx.y * 128, n0 = blockIdx.x * 128;

    f32x4 acc[4][4];
    #pragma unroll
    for (int mt = 0; mt < 4; ++mt)
        #pragma unroll
        for (int nt = 0; nt < 4; ++nt)
            acc[mt][nt] = f32x4{0.f, 0.f, 0.f, 0.f};

    int rowS[2], cS[2];
    #pragma unroll
    for (int t = 0; t < 2; ++t) {
        int idx = t * 256 + tid;
        rowS[t] = idx >> 2;
        cS[t] = idx & 3;
    }

    bf16x8 pa[2], pb[2];
    #pragma unroll
    for (int t = 0; t < 2; ++t) {
        pa[t] = *(const bf16x8*)(A + (size_t)(m0 + rowS[t]) * K + cS[t] * 8);
        pb[t] = *(const bf16x8*)(BT + (size_t)(n0 + rowS[t]) * K + cS[t] * 8);
    }

    const int nk = K / 32;
    for (int kt = 0; kt < nk; ++kt) {
        __syncthreads();
        #pragma unroll
        for (int t = 0; t < 2; ++t) {
            *(bf16x8*)(&As[rowS[t] * 32 + ((cS[t] ^ ((rowS[t] >> 1) & 3)) << 3)]) = pa[t];
            *(bf16x8*)(&Bs[rowS[t] * 32 + ((cS[t] ^ ((rowS[t] >> 1) & 3)) << 3)]) = pb[t];
        }
        __syncthreads();
        if (kt + 1 < nk) {
            int k0 = (kt + 1) * 32;
            #pragma unroll
            for (int t = 0; t < 2; ++t) {
                pa[t] = *(const bf16x8*)(A + (size_t)(m0 + rowS[t]) * K + k0 + cS[t] * 8);
                pb[t] = *(const bf16x8*)(BT + (size_t)(n0 + rowS[t]) * K + k0 + cS[t] * 8);
            }
        }
        bf16x8 af[4], bf[4];
        #pragma unroll
        for (int mt = 0; mt < 4; ++mt) {
            int m = wm * 64 + mt * 16 + lm;
            af[mt] = *(const bf16x8*)(&As[m * 32 + ((quad ^ ((m >> 1) & 3)) << 3)]);
        }
        #pragma unroll
        for (int nt = 0; nt < 4; ++nt) {
            int n = wn * 64 + nt * 16 + lm;
            bf[nt] = *(const bf16x8*)(&Bs[n * 32 + ((quad ^ ((n >> 1) & 3)) << 3)]);
        }
        #pragma unroll
        for (int mt = 0; mt < 4; ++mt)
            #pragma unroll
            for (int nt = 0; nt < 4; ++nt)
                acc[mt][nt] = __builtin_amdgcn_mfma_f32_16x16x32_bf16(
                    af[mt], bf[nt], acc[mt][nt], 0, 0, 0);
    }

    float bv[4];
    #pragma unroll
    for (int nt = 0; nt < 4; ++nt)
        bv[nt] = bias[n0 + wn * 64 + nt * 16 + lm];

    #pragma unroll
    for (int mt = 0; mt < 4; ++mt) {
        #pragma unroll
        for (int nt = 0; nt < 4; ++nt) {
            const int cb = n0 + wn * 64 + nt * 16;     // wave-uniform col block
            const int col = cb + lm;
            const int rbase = m0 + wm * 64 + mt * 16 + quad * 4;
            if (MODE == 0) {
                #pragma unroll
                for (int r = 0; r < 4; ++r)
                    ((float*)Cout)[(size_t)(rbase + r) * N + col] =
                        acc[mt][nt][r] + bv[nt];
            } else if (cb < Csz) {
                // Q -> qb[M][768], scaled
                #pragma unroll
                for (int r = 0; r < 4; ++r)
                    ((unsigned short*)Cout)[(size_t)(rbase + r) * Csz + col] =
                        f2b((acc[mt][nt][r] + bv[nt]) * QSCALE);
            } else if (cb < 2 * Csz) {
                // K -> KP frag-linear
                const int dfull = col - Csz;
                const int h = dfull >> 6, dd = dfull & 63;
                const int f = dd >> 5, qd = (dd >> 3) & 3, j = dd & 7;
                #pragma unroll
                for (int r = 0; r < 4; ++r) {
                    const int row = rbase + r;
                    const int b = row >> 11, t = row & 2047;
                    const int ktk = t >> 4, lmk = t & 15;
                    size_t addr = ((((size_t)((b * Hsz + h) * 128 + ktk)) * 2 + f) * 512)
                                  + (qd * 16 + lmk) * 8 + j;
                    KP[addr] = f2b(acc[mt][nt][r] + bv[nt]);
                }
            } else {
                // V -> VP frag-linear
                const int dfull = col - 2 * Csz;
                const int h = dfull >> 6, dd = dfull & 63;
                const int ntv = dd >> 4, lmv = dd & 15;
                #pragma unroll
                for (int r = 0; r < 4; ++r) {
                    const int row = rbase + r;
                    const int b = row >> 11, t = row & 2047;
                    const int jtv = t >> 5, qv = (t >> 3) & 3, j = t & 7;
                    size_t addr = (((size_t)((b * Hsz + h) * 64 + jtv) * 4 + ntv) * 512)
                                  + (qv * 16 + lmv) * 8 + j;
                    VP[addr] = f2b(acc[mt][nt][r] + bv[nt]);
                }
            }
        }
    }
}

// ---------------------------------------------------------------------------
// MFMA flash attention, dual softmax, NO-MAX variant.
// R12: revert R11's 2-tile P-pipeline (it LOST 3us: VALUBusy 44->37, phase
// batching reduced issue density) back to R7's proven single-tile loop; keep
// qb/KP/VP inputs (R11's epilogue fusion, proven +7us).
// NEW: l-accumulation moved from VALU (64 ops/tile on the 44%-busy pipe)
// back to the ones-column MFMA (4 MFMA/tile on the 13%-busy pipe).
// Numerically identical: both compute l = sum of bf16_trunc(P) (the MFMA
// consumes the SAME truncated-bf16 P frags read back from LDS).
// Butterfly reduce deleted; R0's proven lm==0 + shfl-broadcast epilogue.
// LDS: 18432 B (Pbuf; Mrg overlaid). Tripwires: absmax 0.0039, attn < 53us.
// ---------------------------------------------------------------------------
__global__ __launch_bounds__(256) void attn_mfma(
    const unsigned short* __restrict__ qb, const unsigned short* __restrict__ KP,
    const unsigned short* __restrict__ VP, const float* __restrict__ fsel_arr,
    const float* __restrict__ lw_p, const float* __restrict__ gw_p,
    unsigned short* __restrict__ attnb)
{
    // Union: Pbuf [4][2][16*72] ushort (18432 B) | Mrg [2][2][16][66] f32 (16896 B)
    __shared__ __align__(16) unsigned char SMEM[18432];

    const int tid = threadIdx.x;
    const int widx = tid >> 6, lane = tid & 63;
    const int lm = lane & 15, quad = lane >> 4;

    unsigned short* Pg = (unsigned short*)SMEM + (widx * 2 + 0) * (16 * 72);
    unsigned short* Pl = (unsigned short*)SMEM + (widx * 2 + 1) * (16 * 72);
    float* MrgF = (float*)SMEM;
    // Mrg[slot][branch][row][col], col 0..63 = O, 65 = l (64 unused)
    #define MRG(slot, br, row, col) MrgF[((((slot) * 2 + (br)) * 16 + (row)) * 66) + (col)]

    const int strip = 127 - (int)(blockIdx.x / 24);   // heavy strips first
    const int bh = (int)(blockIdx.x % 24);
    const int h = bh % Hsz, b = bh / Hsz;
    const int i0 = strip * 16;

    const unsigned short* KPb = KP + (size_t)bh * 131072 + lane * 8;
    const unsigned short* VPb = VP + (size_t)bh * 131072 + lane * 8;

    // Q A-frags from qb[M][768]
    const unsigned short* qrow =
        qb + (size_t)(b * Tsz + i0 + lm) * Csz + h * 64 + quad * 8;
    const bf16x8 qf0 = *(const bf16x8*)qrow;
    const bf16x8 qf1 = *(const bf16x8*)(qrow + 32);

    // ones B-frag: B[k][0] = 1 (lanes with lm==0) -> P*B col0 = row sum
    const short o1 = (lm == 0) ? (short)0x3F80 : (short)0;
    const bf16x8 of = bf16x8{o1, o1, o1, o1, o1, o1, o1, o1};

    f32x4 Og[4], Ol[4], lsg, lsl;
    #pragma unroll
    for (int nt = 0; nt < 4; ++nt) {
        Og[nt] = f32x4{0.f, 0.f, 0.f, 0.f};
        Ol[nt] = f32x4{0.f, 0.f, 0.f, 0.f};
    }
    lsg = f32x4{0.f, 0.f, 0.f, 0.f};
    lsl = f32x4{0.f, 0.f, 0.f, 0.f};

    const int jtd = i0 >> 6;                        // diagonal 64-tile
    const int jtl = (jtd - 4) > 0 ? (jtd - 4) : 0;  // first local tile

    for (int jt = widx; jt <= jtd; jt += 4) {
        const int j0 = jt * 64;
        const bool diag = (jt == jtd);
        const bool firstloc = (jt == jtl) && !diag;
        const bool loc = (jt >= jtl);

        // ---- K frags from KP (frag-linear, fully coalesced) ----
        const unsigned short* kp = KPb + (size_t)(j0 >> 4) * 1024;
        bf16x8 kc0[4], kc1[4];
        #pragma unroll
        for (int nt = 0; nt < 4; ++nt) {
            kc0[nt] = *(const bf16x8*)(kp + nt * 1024);
            kc1[nt] = *(const bf16x8*)(kp + nt * 1024 + 512);
        }

        // ---- QK^T ----
        f32x4 s[4];
        #pragma unroll
        for (int nt = 0; nt < 4; ++nt) {
            f32x4 z = f32x4{0.f, 0.f, 0.f, 0.f};
            z = __builtin_amdgcn_mfma_f32_16x16x32_bf16(qf0, kc0[nt], z, 0, 0, 0);
            z = __builtin_amdgcn_mfma_f32_16x16x32_bf16(qf1, kc1[nt], z, 0, 0, 0);
            s[nt] = z;
        }

        float fs[4];
        #pragma unroll
        for (int nt = 0; nt < 4; ++nt)
            fs[nt] = fsel_arr[b * Tsz + j0 + nt * 16 + lm];

        // ---- global branch: P = exp2(s*fs); causal mask only on diag ----
        if (diag) {
            #pragma unroll
            for (int r = 0; r < 4; ++r) {
                const int qi = i0 + quad * 4 + r;
                #pragma unroll
                for (int nt = 0; nt < 4; ++nt) {
                    const int kj = j0 + nt * 16 + lm;
                    float p = fast_exp2(s[nt][r] * fs[nt]);
                    p = (kj > qi) ? 0.f : p;
                    Pg[(quad * 4 + r) * 72 + nt * 16 + lm] =
                        (unsigned short)(__float_as_uint(p) >> 16);
                }
            }
        } else {
            #pragma unroll
            for (int r = 0; r < 4; ++r)
                #pragma unroll
                for (int nt = 0; nt < 4; ++nt) {
                    float p = fast_exp2(s[nt][r] * fs[nt]);
                    Pg[(quad * 4 + r) * 72 + nt * 16 + lm] =
                        (unsigned short)(__float_as_uint(p) >> 16);
                }
        }

        // ---- local branch: P = exp2(s); masks only at diag / first tile ----
        if (loc) {
            if (diag) {
                #pragma unroll
                for (int r = 0; r < 4; ++r) {
                    const int qi = i0 + quad * 4 + r;
                    #pragma unroll
                    for (int nt = 0; nt < 4; ++nt) {
                        const int kj = j0 + nt * 16 + lm;
                        float p = fast_exp2(s[nt][r]);
                        p = (kj > qi || kj < qi - WIN) ? 0.f : p;
                        Pl[(quad * 4 + r) * 72 + nt * 16 + lm] =
                            (unsigned short)(__float_as_uint(p) >> 16);
                    }
                }
            } else if (firstloc) {
                #pragma unroll
                for (int r = 0; r < 4; ++r) {
                    const int qi = i0 + quad * 4 + r;
                    #pragma unroll
                    for (int nt = 0; nt < 4; ++nt) {
                        const int kj = j0 + nt * 16 + lm;
                        float p = fast_exp2(s[nt][r]);
                        p = (kj < qi - WIN) ? 0.f : p;
                        Pl[(quad * 4 + r) * 72 + nt * 16 + lm] =
                            (unsigned short)(__float_as_uint(p) >> 16);
                    }
                }
            } else {
                #pragma unroll
                for (int r = 0; r < 4; ++r)
                    #pragma unroll
                    for (int nt = 0; nt < 4; ++nt) {
                        float p = fast_exp2(s[nt][r]);
                        Pl[(quad * 4 + r) * 72 + nt * 16 + lm] =
                            (unsigned short)(__float_as_uint(p) >> 16);
                    }
            }
        }

        // ---- P A-frags: issue all reads together, once per tile ----
        const bf16x8 ag0 = *(const bf16x8*)(&Pg[lm * 72 + quad * 8]);
        const bf16x8 ag1 = *(const bf16x8*)(&Pg[lm * 72 + 32 + quad * 8]);
        bf16x8 al0 = {}, al1 = {};
        if (loc) {
            al0 = *(const bf16x8*)(&Pl[lm * 72 + quad * 8]);
            al1 = *(const bf16x8*)(&Pl[lm * 72 + 32 + quad * 8]);
        }

        // ---- l via ones-column MFMA (idle matrix pipe, not busy VALU) ----
        lsg = __builtin_amdgcn_mfma_f32_16x16x32_bf16(ag0, of, lsg, 0, 0, 0);
        lsg = __builtin_amdgcn_mfma_f32_16x16x32_bf16(ag1, of, lsg, 0, 0, 0);
        if (loc) {
            lsl = __builtin_amdgcn_mfma_f32_16x16x32_bf16(al0, of, lsl, 0, 0, 0);
            lsl = __builtin_amdgcn_mfma_f32_16x16x32_bf16(al1, of, lsl, 0, 0, 0);
        }

        // ---- V frags from VP (frag-linear, fully coalesced) + PV ----
        const unsigned short* vp = VPb + (size_t)(j0 >> 5) * 2048;
        #pragma unroll
        for (int nt = 0; nt < 4; ++nt) {
            bf16x8 v0 = *(const bf16x8*)(vp + nt * 512);
            bf16x8 v1 = *(const bf16x8*)(vp + 2048 + nt * 512);
            Og[nt] = __builtin_amdgcn_mfma_f32_16x16x32_bf16(ag0, v0, Og[nt], 0, 0, 0);
            Og[nt] = __builtin_amdgcn_mfma_f32_16x16x32_bf16(ag1, v1, Og[nt], 0, 0, 0);
            if (loc) {
                Ol[nt] = __builtin_amdgcn_mfma_f32_16x16x32_bf16(al0, v0, Ol[nt], 0, 0, 0);
                Ol[nt] = __builtin_amdgcn_mfma_f32_16x16x32_bf16(al1, v1, Ol[nt], 0, 0, 0);
            }
        }
    }

    // l lives in lanes lm==0 of lsg/lsl (MFMA row-sum column)
    float l_g[4], l_l[4];
    #pragma unroll
    for (int r = 0; r < 4; ++r) { l_g[r] = lsg[r]; l_l[r] = lsl[r]; }

    // ==== 2-slot pairwise merge tree over the Pbuf/Mrg union ====
    auto write_slot = [&](int slot) {
        #pragma unroll
        for (int r = 0; r < 4; ++r) {
            const int row = quad * 4 + r;
            #pragma unroll
            for (int nt = 0; nt < 4; ++nt) {
                MRG(slot, 0, row, nt * 16 + lm) = Og[nt][r];
                MRG(slot, 1, row, nt * 16 + lm) = Ol[nt][r];
            }
            if (lm == 0) {
                MRG(slot, 0, row, 65) = l_g[r];
                MRG(slot, 1, row, 65) = l_l[r];
            }
        }
    };
    auto combine_slot = [&](int slot) {
        #pragma unroll
        for (int r = 0; r < 4; ++r) {
            const int row = quad * 4 + r;
            {
                l_g[r] += MRG(slot, 0, row, 65);
                #pragma unroll
                for (int nt = 0; nt < 4; ++nt)
                    Og[nt][r] += MRG(slot, 0, row, nt * 16 + lm);
            }
            {
                l_l[r] += MRG(slot, 1, row, 65);
                #pragma unroll
                for (int nt = 0; nt < 4; ++nt)
                    Ol[nt][r] += MRG(slot, 1, row, nt * 16 + lm);
            }
        }
    };

    __syncthreads();          // Pbuf lifetime ends before Mrg overlay begins
    if (widx == 1) write_slot(0);
    if (widx == 3) write_slot(1);
    __syncthreads();
    if (widx == 0) combine_slot(0);
    if (widx == 2) combine_slot(1);
    __syncthreads();
    if (widx == 2) write_slot(0);
    __syncthreads();

    if (widx == 0) {
        combine_slot(0);      // wave 0 now holds the full-strip sums

        // broadcast l from lanes lm==0 (MFMA row-sum column) to all lanes
        #pragma unroll
        for (int r = 0; r < 4; ++r) {
            l_g[r] = __shfl(l_g[r], quad << 4);
            l_l[r] = __shfl(l_l[r], quad << 4);
        }

        float wl = 1.f / (1.f + __expf(-lw_p[0]));
        float wg = 1.f / (1.f + __expf(-gw_p[0]));
        float ws = wl + wg;
        wl /= ws; wg /= ws;

        #pragma unroll
        for (int r = 0; r < 4; ++r) {
            const int row = quad * 4 + r;
            const float cg = wg / l_g[r];
            const float cl = wl / l_l[r];
            #pragma unroll
            for (int nt = 0; nt < 4; ++nt) {
                float v = Og[nt][r] * cg + Ol[nt][r] * cl;
                attnb[(size_t)(b * Tsz + i0 + row) * Csz + h * 64 + nt * 16 + lm] =
                    f2b(v);
            }
        }
    }
    #undef MRG
}

// ---------------------------------------------------------------------------
extern "C" void kernel_launch(void* const* d_in, const int* in_sizes, int n_in,
                              void* d_out, int out_size, void* d_ws, size_t ws_size,
                              hipStream_t stream)
{
    const float* x          = (const float*)d_in[0];
    const float* mamba_raw  = (const float*)d_in[1];
    const float* c_attn_w   = (const float*)d_in[2];
    const float* c_attn_b   = (const float*)d_in[3];
    const float* c_proj_w   = (const float*)d_in[4];
    const float* c_proj_b   = (const float*)d_in[5];
    const float* ln_w       = (const float*)d_in[6];
    const float* ln_b       = (const float*)d_in[7];
    const float* mamba_sc   = (const float*)d_in[8];
    const float* sel_w      = (const float*)d_in[9];
    const float* sel_b      = (const float*)d_in[10];
    const float* local_w    = (const float*)d_in[11];
    const float* global_w   = (const float*)d_in[12];
    float* out = (float*)d_out;

    const int M = Bsz * Tsz;                 // 4096

    // Workspace layout (ushort units)
    unsigned short* xb    = (unsigned short*)d_ws;       // 4096*768
    unsigned short* wq    = xb + (size_t)M * Csz;        // 2304*768 (c_attn_w^T)
    unsigned short* wp    = wq + (size_t)C3 * Csz;       // 768*768  (c_proj_w^T)
    unsigned short* qb    = wp + (size_t)Csz * Csz;      // 4096*768 (Q only)
    unsigned short* kpb   = qb + (size_t)M * Csz;        // 24*131072
    unsigned short* vpb   = kpb + (size_t)24 * 131072;   // 24*131072
    unsigned short* attnb = vpb + (size_t)24 * 131072;   // 4096*768
    float* sel = (float*)(attnb + (size_t)M * Csz);      // 4096

    // 1) fused prep: convert + both weight transposes + selector
    prep_fused<<<9472, 256, 0, stream>>>(x, xb, c_attn_w, wq, c_proj_w, wp,
                                         mamba_raw, ln_w, ln_b, mamba_sc,
                                         sel_w, sel_b, sel);

    // 2) QKV projection: Q -> qb (scaled), K -> KP, V -> VP (frag-linear)
    {
        dim3 g(C3 / 128, M / 128);
        gemm_bt_mfma<1><<<g, 256, 0, stream>>>(xb, wq, c_attn_b, qb,
                                               kpb, vpb, M, C3, Csz);
    }

    // 3) attention (bf16 out): one block per strip per (b,h)
    attn_mfma<<<128 * Hsz * Bsz, 256, 0, stream>>>(qb, kpb, vpb, sel,
                                                   local_w, global_w, attnb);

    // 4) output projection (fp32 out)
    {
        dim3 g(Csz / 128, M / 128);
        gemm_bt_mfma<0><<<g, 256, 0, stream>>>(attnb, wp, c_proj_b, out,
                                               nullptr, nullptr, M, Csz, Csz);
    }
}

// Round 14
// 192.845 us; speedup vs baseline: 1.0219x; 1.0219x over previous
//
#include <hip/hip_runtime.h>
#include <math.h>

// Problem constants
#define Bsz 2
#define Tsz 2048
#define Csz 768
#define Hsz 12
#define C3  2304      // 3*C
#define WIN 256
#define LN_EPS 1e-5f

// Q pre-scale: D^-0.5 * log2(e), folded into the QKV GEMM epilogue so the
// attention kernel works in the exp2 domain with no per-element multiplies.
#define QSCALE 0.1803368801111137f

typedef short bf16x8 __attribute__((ext_vector_type(8)));  // 8 bf16 (4 VGPRs)
typedef float f32x4  __attribute__((ext_vector_type(4)));

// fp32 -> bf16 round-to-nearest-even
__device__ __forceinline__ unsigned short f2b(float f) {
    unsigned int u = __float_as_uint(f);
    u = (u + 0x7fffu + ((u >> 16) & 1u)) >> 16;
    return (unsigned short)u;
}

// raw v_exp_f32 (exp2). ocml exp2f without fast-math adds ~5 insts of
// denormal fixup; inputs here are |x| <~ 12, nothing denormal matters.
__device__ __forceinline__ float fast_exp2(float x) {
    float r;
    asm("v_exp_f32 %0, %1" : "=v"(r) : "v"(x));
    return r;
}

// ---------------------------------------------------------------------------
// Fused prep: convert_bf16 | transpose_conv(wq) | transpose_conv(wp) | sel.
// Block ranges: [0,3072) convert; [3072,4800) wq-transpose (72x24);
// [4800,5376) wp-transpose (24x24); [5376,9472) sel rows.
// ---------------------------------------------------------------------------
__global__ __launch_bounds__(256) void prep_fused(
    const float* __restrict__ x, unsigned short* __restrict__ xb,
    const float* __restrict__ c_attn_w, unsigned short* __restrict__ wq,
    const float* __restrict__ c_proj_w, unsigned short* __restrict__ wp,
    const float* __restrict__ mr, const float* __restrict__ ln_w,
    const float* __restrict__ ln_b, const float* __restrict__ scale_p,
    const float* __restrict__ sel_w, const float* __restrict__ sel_b,
    float* __restrict__ sel)
{
    __shared__ float tile[32][33];
    __shared__ float red1[256];
    __shared__ float red2[256];
    __shared__ float mu_sh, rstd_sh;

    const int blk = blockIdx.x;
    const int tid = threadIdx.x;

    if (blk < 3072) {
        int idx = blk * 256 + tid;
        float4 v = *(const float4*)(x + (size_t)idx * 4);
        unsigned int lo = (unsigned int)f2b(v.x) | ((unsigned int)f2b(v.y) << 16);
        unsigned int hi = (unsigned int)f2b(v.z) | ((unsigned int)f2b(v.w) << 16);
        uint2 o; o.x = lo; o.y = hi;
        *(uint2*)(xb + (size_t)idx * 4) = o;
        return;
    }
    if (blk < 5376) {
        const float* src; unsigned short* dst; int K, N, n0, k0;
        if (blk < 4800) {
            int i = blk - 3072;             // wq: grid (72, 24)
            src = c_attn_w; dst = wq; K = Csz; N = C3;
            n0 = (i % 72) * 32; k0 = (i / 72) * 32;
        } else {
            int i = blk - 4800;             // wp: grid (24, 24)
            src = c_proj_w; dst = wp; K = Csz; N = Csz;
            n0 = (i % 24) * 32; k0 = (i / 24) * 32;
        }
        const int tx = tid & 31, ty = tid >> 5;   // 32 x 8
        #pragma unroll
        for (int p = 0; p < 4; ++p)
            tile[ty + p * 8][tx] = src[(size_t)(k0 + ty + p * 8) * N + n0 + tx];
        __syncthreads();
        #pragma unroll
        for (int p = 0; p < 4; ++p)
            dst[(size_t)(n0 + ty + p * 8) * K + k0 + tx] = f2b(tile[tx][ty + p * 8]);
        return;
    }

    const int r = blk - 5376;
    const float* row = mr + (size_t)r * Csz;

    float s = 0.f, s2 = 0.f;
    for (int c = tid; c < Csz; c += 256) {
        float xv = row[c];
        s += xv; s2 += xv * xv;
    }
    red1[tid] = s; red2[tid] = s2;
    __syncthreads();
    for (int st = 128; st > 0; st >>= 1) {
        if (tid < st) { red1[tid] += red1[tid + st]; red2[tid] += red2[tid + st]; }
        __syncthreads();
    }
    if (tid == 0) {
        float mu = red1[0] * (1.f / Csz);
        float var = red2[0] * (1.f / Csz) - mu * mu;
        mu_sh = mu;
        rstd_sh = rsqrtf(var + LN_EPS);
    }
    __syncthreads();
    const float mu = mu_sh, rstd = rstd_sh;

    float dot = 0.f;
    for (int c = tid; c < Csz; c += 256) {
        float xn = (row[c] - mu) * rstd * ln_w[c] + ln_b[c];
        dot += xn * sel_w[c];
    }
    red1[tid] = dot;
    __syncthreads();
    for (int st = 128; st > 0; st >>= 1) {
        if (tid < st) red1[tid] += red1[tid + st];
        __syncthreads();
    }
    if (tid == 0) {
        float z = scale_p[0] * red1[0] + sel_b[0];
        sel[r] = 0.5f + 0.5f / (1.f + __expf(-z));
    }
}

// ---------------------------------------------------------------------------
// bf16 MFMA GEMM, B^T input. Two epilogue MODEs (R11, proven).
// MODE 0 (proj): C fp32 = acc + bias.
// MODE 1 (QKV): Q (bf16, *QSCALE) -> qb[M][768]; K/V directly in KP/VP
//   frag-linear order (inverse pack mappings). Main loop = R7 structure.
// ---------------------------------------------------------------------------
template<int MODE>
__global__ __launch_bounds__(256) void gemm_bt_mfma(
    const unsigned short* __restrict__ A, const unsigned short* __restrict__ BT,
    const float* __restrict__ bias, void* __restrict__ Cout,
    unsigned short* __restrict__ KP, unsigned short* __restrict__ VP,
    int M, int N, int K)
{
    __shared__ unsigned short As[128 * 32];
    __shared__ unsigned short Bs[128 * 32];

    const int tid = threadIdx.x;
    const int lane = tid & 63, widx = tid >> 6;
    const int lm = lane & 15, quad = lane >> 4;
    const int wm = widx >> 1, wn = widx & 1;
    const int m0 = blockIdx.y * 128, n0 = blockIdx.x * 128;

    f32x4 acc[4][4];
    #pragma unroll
    for (int mt = 0; mt < 4; ++mt)
        #pragma unroll
        for (int nt = 0; nt < 4; ++nt)
            acc[mt][nt] = f32x4{0.f, 0.f, 0.f, 0.f};

    int rowS[2], cS[2];
    #pragma unroll
    for (int t = 0; t < 2; ++t) {
        int idx = t * 256 + tid;
        rowS[t] = idx >> 2;
        cS[t] = idx & 3;
    }

    bf16x8 pa[2], pb[2];
    #pragma unroll
    for (int t = 0; t < 2; ++t) {
        pa[t] = *(const bf16x8*)(A + (size_t)(m0 + rowS[t]) * K + cS[t] * 8);
        pb[t] = *(const bf16x8*)(BT + (size_t)(n0 + rowS[t]) * K + cS[t] * 8);
    }

    const int nk = K / 32;
    for (int kt = 0; kt < nk; ++kt) {
        __syncthreads();
        #pragma unroll
        for (int t = 0; t < 2; ++t) {
            *(bf16x8*)(&As[rowS[t] * 32 + ((cS[t] ^ ((rowS[t] >> 1) & 3)) << 3)]) = pa[t];
            *(bf16x8*)(&Bs[rowS[t] * 32 + ((cS[t] ^ ((rowS[t] >> 1) & 3)) << 3)]) = pb[t];
        }
        __syncthreads();
        if (kt + 1 < nk) {
            int k0 = (kt + 1) * 32;
            #pragma unroll
            for (int t = 0; t < 2; ++t) {
                pa[t] = *(const bf16x8*)(A + (size_t)(m0 + rowS[t]) * K + k0 + cS[t] * 8);
                pb[t] = *(const bf16x8*)(BT + (size_t)(n0 + rowS[t]) * K + k0 + cS[t] * 8);
            }
        }
        bf16x8 af[4], bf[4];
        #pragma unroll
        for (int mt = 0; mt < 4; ++mt) {
            int m = wm * 64 + mt * 16 + lm;
            af[mt] = *(const bf16x8*)(&As[m * 32 + ((quad ^ ((m >> 1) & 3)) << 3)]);
        }
        #pragma unroll
        for (int nt = 0; nt < 4; ++nt) {
            int n = wn * 64 + nt * 16 + lm;
            bf[nt] = *(const bf16x8*)(&Bs[n * 32 + ((quad ^ ((n >> 1) & 3)) << 3)]);
        }
        #pragma unroll
        for (int mt = 0; mt < 4; ++mt)
            #pragma unroll
            for (int nt = 0; nt < 4; ++nt)
                acc[mt][nt] = __builtin_amdgcn_mfma_f32_16x16x32_bf16(
                    af[mt], bf[nt], acc[mt][nt], 0, 0, 0);
    }

    float bv[4];
    #pragma unroll
    for (int nt = 0; nt < 4; ++nt)
        bv[nt] = bias[n0 + wn * 64 + nt * 16 + lm];

    #pragma unroll
    for (int mt = 0; mt < 4; ++mt) {
        #pragma unroll
        for (int nt = 0; nt < 4; ++nt) {
            const int cb = n0 + wn * 64 + nt * 16;     // wave-uniform col block
            const int col = cb + lm;
            const int rbase = m0 + wm * 64 + mt * 16 + quad * 4;
            if (MODE == 0) {
                #pragma unroll
                for (int r = 0; r < 4; ++r)
                    ((float*)Cout)[(size_t)(rbase + r) * N + col] =
                        acc[mt][nt][r] + bv[nt];
            } else if (cb < Csz) {
                // Q -> qb[M][768], scaled
                #pragma unroll
                for (int r = 0; r < 4; ++r)
                    ((unsigned short*)Cout)[(size_t)(rbase + r) * Csz + col] =
                        f2b((acc[mt][nt][r] + bv[nt]) * QSCALE);
            } else if (cb < 2 * Csz) {
                // K -> KP frag-linear
                const int dfull = col - Csz;
                const int h = dfull >> 6, dd = dfull & 63;
                const int f = dd >> 5, qd = (dd >> 3) & 3, j = dd & 7;
                #pragma unroll
                for (int r = 0; r < 4; ++r) {
                    const int row = rbase + r;
                    const int b = row >> 11, t = row & 2047;
                    const int ktk = t >> 4, lmk = t & 15;
                    size_t addr = ((((size_t)((b * Hsz + h) * 128 + ktk)) * 2 + f) * 512)
                                  + (qd * 16 + lmk) * 8 + j;
                    KP[addr] = f2b(acc[mt][nt][r] + bv[nt]);
                }
            } else {
                // V -> VP frag-linear
                const int dfull = col - 2 * Csz;
                const int h = dfull >> 6, dd = dfull & 63;
                const int ntv = dd >> 4, lmv = dd & 15;
                #pragma unroll
                for (int r = 0; r < 4; ++r) {
                    const int row = rbase + r;
                    const int b = row >> 11, t = row & 2047;
                    const int jtv = t >> 5, qv = (t >> 3) & 3, j = t & 7;
                    size_t addr = (((size_t)((b * Hsz + h) * 64 + jtv) * 4 + ntv) * 512)
                                  + (qv * 16 + lmv) * 8 + j;
                    VP[addr] = f2b(acc[mt][nt][r] + bv[nt]);
                }
            }
        }
    }
}

// ---------------------------------------------------------------------------
// MFMA flash attention, dual softmax, NO-MAX variant.
// R13: compose the two proven winners (never benched together):
//  - R7's exact single-tile loop with VALU-l accumulation + butterfly
//    (proven 53us; R12's MFMA-l serial chain cost +13us - reverted).
//  - qb/KP/VP inputs from the R11 GEMM-epilogue pack (proven -7us non-attn).
// Structure: dual-branch 4 waves, stride 4, LDS union, fast_exp2, mask
// elision. LDS: 18432 B. Tripwires: VGPR ~60, WRITE_SIZE 6144, attn ~53us.
// ---------------------------------------------------------------------------
__global__ __launch_bounds__(256) void attn_mfma(
    const unsigned short* __restrict__ qb, const unsigned short* __restrict__ KP,
    const unsigned short* __restrict__ VP, const float* __restrict__ fsel_arr,
    const float* __restrict__ lw_p, const float* __restrict__ gw_p,
    unsigned short* __restrict__ attnb)
{
    // Union: Pbuf [4][2][16*72] ushort (18432 B) | Mrg [2][2][16][66] f32 (16896 B)
    __shared__ __align__(16) unsigned char SMEM[18432];

    const int tid = threadIdx.x;
    const int widx = tid >> 6, lane = tid & 63;
    const int lm = lane & 15, quad = lane >> 4;

    unsigned short* Pg = (unsigned short*)SMEM + (widx * 2 + 0) * (16 * 72);
    unsigned short* Pl = (unsigned short*)SMEM + (widx * 2 + 1) * (16 * 72);
    float* MrgF = (float*)SMEM;
    // Mrg[slot][branch][row][col], col 0..63 = O, 65 = l (64 unused)
    #define MRG(slot, br, row, col) MrgF[((((slot) * 2 + (br)) * 16 + (row)) * 66) + (col)]

    const int strip = 127 - (int)(blockIdx.x / 24);   // heavy strips first
    const int bh = (int)(blockIdx.x % 24);
    const int h = bh % Hsz, b = bh / Hsz;
    const int i0 = strip * 16;

    const unsigned short* KPb = KP + (size_t)bh * 131072 + lane * 8;
    const unsigned short* VPb = VP + (size_t)bh * 131072 + lane * 8;

    // Q A-frags from qb[M][768]
    const unsigned short* qrow =
        qb + (size_t)(b * Tsz + i0 + lm) * Csz + h * 64 + quad * 8;
    const bf16x8 qf0 = *(const bf16x8*)qrow;
    const bf16x8 qf1 = *(const bf16x8*)(qrow + 32);

    float l_g[4], l_l[4];                       // per-lane partial row sums
    f32x4 Og[4], Ol[4];
    #pragma unroll
    for (int r = 0; r < 4; ++r) { l_g[r] = 0.f; l_l[r] = 0.f; }
    #pragma unroll
    for (int nt = 0; nt < 4; ++nt) {
        Og[nt] = f32x4{0.f, 0.f, 0.f, 0.f};
        Ol[nt] = f32x4{0.f, 0.f, 0.f, 0.f};
    }

    const int jtd = i0 >> 6;                        // diagonal 64-tile
    const int jtl = (jtd - 4) > 0 ? (jtd - 4) : 0;  // first local tile

    for (int jt = widx; jt <= jtd; jt += 4) {
        const int j0 = jt * 64;
        const bool diag = (jt == jtd);
        const bool firstloc = (jt == jtl) && !diag;
        const bool loc = (jt >= jtl);

        // ---- K frags from KP (frag-linear, fully coalesced) ----
        const unsigned short* kp = KPb + (size_t)(j0 >> 4) * 1024;
        bf16x8 kc0[4], kc1[4];
        #pragma unroll
        for (int nt = 0; nt < 4; ++nt) {
            kc0[nt] = *(const bf16x8*)(kp + nt * 1024);
            kc1[nt] = *(const bf16x8*)(kp + nt * 1024 + 512);
        }

        // ---- QK^T ----
        f32x4 s[4];
        #pragma unroll
        for (int nt = 0; nt < 4; ++nt) {
            f32x4 z = f32x4{0.f, 0.f, 0.f, 0.f};
            z = __builtin_amdgcn_mfma_f32_16x16x32_bf16(qf0, kc0[nt], z, 0, 0, 0);
            z = __builtin_amdgcn_mfma_f32_16x16x32_bf16(qf1, kc1[nt], z, 0, 0, 0);
            s[nt] = z;
        }

        float fs[4];
        #pragma unroll
        for (int nt = 0; nt < 4; ++nt)
            fs[nt] = fsel_arr[b * Tsz + j0 + nt * 16 + lm];

        // ---- global branch: P = exp2(s*fs); causal mask only on diag ----
        if (diag) {
            #pragma unroll
            for (int r = 0; r < 4; ++r) {
                const int qi = i0 + quad * 4 + r;
                #pragma unroll
                for (int nt = 0; nt < 4; ++nt) {
                    const int kj = j0 + nt * 16 + lm;
                    float p = fast_exp2(s[nt][r] * fs[nt]);
                    p = (kj > qi) ? 0.f : p;
                    unsigned int u = __float_as_uint(p);
                    l_g[r] += __uint_as_float(u & 0xffff0000u);
                    Pg[(quad * 4 + r) * 72 + nt * 16 + lm] = (unsigned short)(u >> 16);
                }
            }
        } else {
            #pragma unroll
            for (int r = 0; r < 4; ++r)
                #pragma unroll
                for (int nt = 0; nt < 4; ++nt) {
                    float p = fast_exp2(s[nt][r] * fs[nt]);
                    unsigned int u = __float_as_uint(p);
                    l_g[r] += __uint_as_float(u & 0xffff0000u);
                    Pg[(quad * 4 + r) * 72 + nt * 16 + lm] = (unsigned short)(u >> 16);
                }
        }

        // ---- local branch: P = exp2(s); masks only at diag / first tile ----
        if (loc) {
            if (diag) {
                #pragma unroll
                for (int r = 0; r < 4; ++r) {
                    const int qi = i0 + quad * 4 + r;
                    #pragma unroll
                    for (int nt = 0; nt < 4; ++nt) {
                        const int kj = j0 + nt * 16 + lm;
                        float p = fast_exp2(s[nt][r]);
                        p = (kj > qi || kj < qi - WIN) ? 0.f : p;
                        unsigned int u = __float_as_uint(p);
                        l_l[r] += __uint_as_float(u & 0xffff0000u);
                        Pl[(quad * 4 + r) * 72 + nt * 16 + lm] = (unsigned short)(u >> 16);
                    }
                }
            } else if (firstloc) {
                #pragma unroll
                for (int r = 0; r < 4; ++r) {
                    const int qi = i0 + quad * 4 + r;
                    #pragma unroll
                    for (int nt = 0; nt < 4; ++nt) {
                        const int kj = j0 + nt * 16 + lm;
                        float p = fast_exp2(s[nt][r]);
                        p = (kj < qi - WIN) ? 0.f : p;
                        unsigned int u = __float_as_uint(p);
                        l_l[r] += __uint_as_float(u & 0xffff0000u);
                        Pl[(quad * 4 + r) * 72 + nt * 16 + lm] = (unsigned short)(u >> 16);
                    }
                }
            } else {
                #pragma unroll
                for (int r = 0; r < 4; ++r)
                    #pragma unroll
                    for (int nt = 0; nt < 4; ++nt) {
                        float p = fast_exp2(s[nt][r]);
                        unsigned int u = __float_as_uint(p);
                        l_l[r] += __uint_as_float(u & 0xffff0000u);
                        Pl[(quad * 4 + r) * 72 + nt * 16 + lm] = (unsigned short)(u >> 16);
                    }
            }
        }

        // ---- P A-frags: issue all reads together, once per tile ----
        const bf16x8 ag0 = *(const bf16x8*)(&Pg[lm * 72 + quad * 8]);
        const bf16x8 ag1 = *(const bf16x8*)(&Pg[lm * 72 + 32 + quad * 8]);
        bf16x8 al0 = {}, al1 = {};
        if (loc) {
            al0 = *(const bf16x8*)(&Pl[lm * 72 + quad * 8]);
            al1 = *(const bf16x8*)(&Pl[lm * 72 + 32 + quad * 8]);
        }

        // ---- V frags from VP (frag-linear, fully coalesced) + PV ----
        const unsigned short* vp = VPb + (size_t)(j0 >> 5) * 2048;
        #pragma unroll
        for (int nt = 0; nt < 4; ++nt) {
            bf16x8 v0 = *(const bf16x8*)(vp + nt * 512);
            bf16x8 v1 = *(const bf16x8*)(vp + 2048 + nt * 512);
            Og[nt] = __builtin_amdgcn_mfma_f32_16x16x32_bf16(ag0, v0, Og[nt], 0, 0, 0);
            Og[nt] = __builtin_amdgcn_mfma_f32_16x16x32_bf16(ag1, v1, Og[nt], 0, 0, 0);
            if (loc) {
                Ol[nt] = __builtin_amdgcn_mfma_f32_16x16x32_bf16(al0, v0, Ol[nt], 0, 0, 0);
                Ol[nt] = __builtin_amdgcn_mfma_f32_16x16x32_bf16(al1, v1, Ol[nt], 0, 0, 0);
            }
        }
    }

    // ---- reduce l partials over the 16 lm lanes (butterfly, all lanes get sum)
    #pragma unroll
    for (int st = 1; st < 16; st <<= 1) {
        #pragma unroll
        for (int r = 0; r < 4; ++r) {
            l_g[r] += __shfl_xor(l_g[r], st);
            l_l[r] += __shfl_xor(l_l[r], st);
        }
    }

    // ==== 2-slot pairwise merge tree over the Pbuf/Mrg union ====
    auto write_slot = [&](int slot) {
        #pragma unroll
        for (int r = 0; r < 4; ++r) {
            const int row = quad * 4 + r;
            #pragma unroll
            for (int nt = 0; nt < 4; ++nt) {
                MRG(slot, 0, row, nt * 16 + lm) = Og[nt][r];
                MRG(slot, 1, row, nt * 16 + lm) = Ol[nt][r];
            }
            if (lm == 0) {
                MRG(slot, 0, row, 65) = l_g[r];
                MRG(slot, 1, row, 65) = l_l[r];
            }
        }
    };
    auto combine_slot = [&](int slot) {
        #pragma unroll
        for (int r = 0; r < 4; ++r) {
            const int row = quad * 4 + r;
            {
                l_g[r] += MRG(slot, 0, row, 65);
                #pragma unroll
                for (int nt = 0; nt < 4; ++nt)
                    Og[nt][r] += MRG(slot, 0, row, nt * 16 + lm);
            }
            {
                l_l[r] += MRG(slot, 1, row, 65);
                #pragma unroll
                for (int nt = 0; nt < 4; ++nt)
                    Ol[nt][r] += MRG(slot, 1, row, nt * 16 + lm);
            }
        }
    };

    __syncthreads();          // Pbuf lifetime ends before Mrg overlay begins
    if (widx == 1) write_slot(0);
    if (widx == 3) write_slot(1);
    __syncthreads();
    if (widx == 0) combine_slot(0);
    if (widx == 2) combine_slot(1);
    __syncthreads();
    if (widx == 2) write_slot(0);
    __syncthreads();

    if (widx == 0) {
        combine_slot(0);      // wave 0 now holds the full-strip sums

        float wl = 1.f / (1.f + __expf(-lw_p[0]));
        float wg = 1.f / (1.f + __expf(-gw_p[0]));
        float ws = wl + wg;
        wl /= ws; wg /= ws;

        #pragma unroll
        for (int r = 0; r < 4; ++r) {
            const int row = quad * 4 + r;
            const float cg = wg / l_g[r];
            const float cl = wl / l_l[r];
            #pragma unroll
            for (int nt = 0; nt < 4; ++nt) {
                float v = Og[nt][r] * cg + Ol[nt][r] * cl;
                attnb[(size_t)(b * Tsz + i0 + row) * Csz + h * 64 + nt * 16 + lm] =
                    f2b(v);
            }
        }
    }
    #undef MRG
}

// ---------------------------------------------------------------------------
extern "C" void kernel_launch(void* const* d_in, const int* in_sizes, int n_in,
                              void* d_out, int out_size, void* d_ws, size_t ws_size,
                              hipStream_t stream)
{
    const float* x          = (const float*)d_in[0];
    const float* mamba_raw  = (const float*)d_in[1];
    const float* c_attn_w   = (const float*)d_in[2];
    const float* c_attn_b   = (const float*)d_in[3];
    const float* c_proj_w   = (const float*)d_in[4];
    const float* c_proj_b   = (const float*)d_in[5];
    const float* ln_w       = (const float*)d_in[6];
    const float* ln_b       = (const float*)d_in[7];
    const float* mamba_sc   = (const float*)d_in[8];
    const float* sel_w      = (const float*)d_in[9];
    const float* sel_b      = (const float*)d_in[10];
    const float* local_w    = (const float*)d_in[11];
    const float* global_w   = (const float*)d_in[12];
    float* out = (float*)d_out;

    const int M = Bsz * Tsz;                 // 4096

    // Workspace layout (ushort units)
    unsigned short* xb    = (unsigned short*)d_ws;       // 4096*768
    unsigned short* wq    = xb + (size_t)M * Csz;        // 2304*768 (c_attn_w^T)
    unsigned short* wp    = wq + (size_t)C3 * Csz;       // 768*768  (c_proj_w^T)
    unsigned short* qb    = wp + (size_t)Csz * Csz;      // 4096*768 (Q only)
    unsigned short* kpb   = qb + (size_t)M * Csz;        // 24*131072
    unsigned short* vpb   = kpb + (size_t)24 * 131072;   // 24*131072
    unsigned short* attnb = vpb + (size_t)24 * 131072;   // 4096*768
    float* sel = (float*)(attnb + (size_t)M * Csz);      // 4096

    // 1) fused prep: convert + both weight transposes + selector
    prep_fused<<<9472, 256, 0, stream>>>(x, xb, c_attn_w, wq, c_proj_w, wp,
                                         mamba_raw, ln_w, ln_b, mamba_sc,
                                         sel_w, sel_b, sel);

    // 2) QKV projection: Q -> qb (scaled), K -> KP, V -> VP (frag-linear)
    {
        dim3 g(C3 / 128, M / 128);
        gemm_bt_mfma<1><<<g, 256, 0, stream>>>(xb, wq, c_attn_b, qb,
                                               kpb, vpb, M, C3, Csz);
    }

    // 3) attention (bf16 out): one block per strip per (b,h)
    attn_mfma<<<128 * Hsz * Bsz, 256, 0, stream>>>(qb, kpb, vpb, sel,
                                                   local_w, global_w, attnb);

    // 4) output projection (fp32 out)
    {
        dim3 g(Csz / 128, M / 128);
        gemm_bt_mfma<0><<<g, 256, 0, stream>>>(attnb, wp, c_proj_b, out,
                                               nullptr, nullptr, M, Csz, Csz);
    }
}